// Round 12
// baseline (166.411 us; speedup 1.0000x reference)
//
#include <hip/hip_runtime.h>
#include <hip/hip_bf16.h>

// Problem constants
#define BB 2
#define SS 2048
#define DD 1024
#define HH 16
#define MMR (BB*SS)   // 4096 rows
#define ND3 3072      // fused QKV width

typedef __hip_bfloat16 bf;
typedef __bf16 bf16x8 __attribute__((ext_vector_type(8)));
typedef float f32x4 __attribute__((ext_vector_type(4)));
typedef float f32x16 __attribute__((ext_vector_type(16)));

#define VMCNT(n) asm volatile("s_waitcnt vmcnt(" #n ")" ::: "memory")

__device__ __forceinline__ f32x4 mfma16(bf16x8 a, bf16x8 b, f32x4 c) {
    return __builtin_amdgcn_mfma_f32_16x16x32_bf16(a, b, c, 0, 0, 0);
}
__device__ __forceinline__ f32x16 mfma32(bf16x8 a, bf16x8 b, f32x16 c) {
    return __builtin_amdgcn_mfma_f32_32x32x16_bf16(a, b, c, 0, 0, 0);
}
__device__ __forceinline__ unsigned cvt_pk_bf16(float lo, float hi) {
    unsigned r;
    asm("v_cvt_pk_bf16_f32 %0, %1, %2" : "=v"(r) : "v"(lo), "v"(hi));
    return r;
}
// after: a = {a.lo31, b.lo31}, b = {a.hi31, b.hi31}
__device__ __forceinline__ void pl32swap(unsigned& a, unsigned& b) {
    asm("v_permlane32_swap_b32 %0, %1" : "+v"(a), "+v"(b));
}
// async global->LDS, 16B/lane; LDS dest = wave-uniform base + lane*16
__device__ __forceinline__ void glds16(const bf* g, bf* l) {
    __builtin_amdgcn_global_load_lds(
        (const __attribute__((address_space(1))) void*)g,
        (__attribute__((address_space(3))) void*)l,
        16, 0, 0);
}

// ---------------------------------------------------------------
// All f32->bf16 converts in ONE launch. blocks 0..4095: X (4M elems);
// blocks 4096..8191: Wq,Wk,Wv (into Wqkv) and Wo (into Wob), 1M each.
__global__ __launch_bounds__(256) void k_convert(const float* __restrict__ X,
                                                 const float* __restrict__ Wq,
                                                 const float* __restrict__ Wk,
                                                 const float* __restrict__ Wv,
                                                 const float* __restrict__ Wo,
                                                 bf* __restrict__ Xb,
                                                 bf* __restrict__ Wqkv,
                                                 bf* __restrict__ Wob) {
    const int bid = blockIdx.x;
    const float* src;
    bf* dst;
    int off;
    if (bid < 4096) {
        src = X; dst = Xb; off = bid;
    } else {
        const int r = (bid - 4096) >> 10;
        src = (r == 0) ? Wq : (r == 1) ? Wk : (r == 2) ? Wv : Wo;
        dst = (r < 3) ? (Wqkv + (size_t)r * 1048576) : Wob;
        off = (bid - 4096) & 1023;
    }
    const int j = (off * 256 + threadIdx.x) * 4;
    float4 v = *(const float4*)(src + j);
    bf tmp[4];
    tmp[0] = __float2bfloat16(v.x);
    tmp[1] = __float2bfloat16(v.y);
    tmp[2] = __float2bfloat16(v.z);
    tmp[3] = __float2bfloat16(v.w);
    *(uint2*)(dst + j) = *(const uint2*)tmp;
}

// ---------------------------------------------------------------
// QKV GEMM (r7/r10-proven): 128x128 tile, BK=32, 8 waves (512 thr),
// wave = 32x64 quadrant. 3-buffer LDS pipeline, counted vmcnt, raw s_barrier,
// seg-XOR LDS swizzle. 768 blocks x 8 waves = 24 waves/CU.
// Fused epilogue: cols<2048 -> per-head L2-norm * mask -> Qn/Kn [B*H,S,64];
// cols>=2048 -> transposed bf16 write to Vt [B*H,64,S].
__global__ __launch_bounds__(512, 6) void k_gemm8(const bf* __restrict__ A,
                                                  const bf* __restrict__ Bt,
                                                  const int* __restrict__ masks,
                                                  bf* __restrict__ Qn,
                                                  bf* __restrict__ Kn,
                                                  bf* __restrict__ Vt,
                                                  int nx, int K) {
    __shared__ __align__(16) bf Asm[3][128 * 32];
    __shared__ __align__(16) bf Bsm[3][128 * 32];
    const int tid = threadIdx.x;
    const int w = tid >> 6, lane = tid & 63, g = lane >> 4, rl = lane & 15;
    const int cpx = gridDim.x >> 3;
    const int swz = (blockIdx.x & 7) * cpx + (blockIdx.x >> 3);
    const int m0 = (swz / nx) * 128, n0 = (swz % nx) * 128;
    const int wr = (w >> 1) * 32, wc = (w & 1) * 64;
    const int lrow = lane >> 2, lseg = lane & 3;
    const int xseg = lseg ^ ((lrow >> 1) & 3);   // pre-swizzled source seg

    f32x4 acc[2][4] = {};
    const bf* Ap = A + (size_t)m0 * K;
    const bf* Bp = Bt + (size_t)n0 * K;

    auto stage = [&](int bi, int k0) {
        glds16(Ap + (size_t)(w * 16 + lrow) * K + k0 + xseg * 8, &Asm[bi][w * 512]);
        glds16(Bp + (size_t)(w * 16 + lrow) * K + k0 + xseg * 8, &Bsm[bi][w * 512]);
    };

    const int T = K >> 5;
    stage(0, 0);
    stage(1, 32);
    int cur = 0, nxt = 2;
    for (int t = 0; t < T; ++t) {
        __builtin_amdgcn_sched_barrier(0);
        if (t < T - 1) { VMCNT(2); } else { VMCNT(0); }
        __builtin_amdgcn_s_barrier();     // staged loads stay in flight
        __builtin_amdgcn_sched_barrier(0);
        if (t + 2 < T) stage(nxt, (t + 2) * 32);

        const bf* Ab = Asm[cur];
        const bf* Bb = Bsm[cur];
        bf16x8 af[2], bfr[4];
#pragma unroll
        for (int m = 0; m < 2; ++m) {
            const int row = wr + m * 16 + rl;
            af[m] = __builtin_bit_cast(bf16x8,
                *(const int4*)&Ab[row * 32 + (g ^ ((row >> 1) & 3)) * 8]);
        }
#pragma unroll
        for (int n = 0; n < 4; ++n) {
            const int row = wc + n * 16 + rl;
            bfr[n] = __builtin_bit_cast(bf16x8,
                *(const int4*)&Bb[row * 32 + (g ^ ((row >> 1) & 3)) * 8]);
        }
        __builtin_amdgcn_s_setprio(1);
#pragma unroll
        for (int m = 0; m < 2; ++m)
#pragma unroll
            for (int n = 0; n < 4; ++n)
                acc[m][n] = mfma16(af[m], bfr[n], acc[m][n]);
        __builtin_amdgcn_s_setprio(0);

        cur = (cur == 2) ? 0 : cur + 1;
        nxt = (nxt == 2) ? 0 : nxt + 1;
    }

    const int ncol0 = n0 + wc;   // wave's 64-col base == one head slice
    if (ncol0 < 2048) {
        bf* dst = (ncol0 < 1024) ? Qn : Kn;
        const int h2 = (ncol0 >> 6) & 15;
#pragma unroll
        for (int m = 0; m < 2; ++m) {
#pragma unroll
            for (int ri = 0; ri < 4; ++ri) {
                const int row = m0 + wr + m * 16 + g * 4 + ri;   // b*S+s
                float ss = 0.f;
#pragma unroll
                for (int n = 0; n < 4; ++n) ss += acc[m][n][ri] * acc[m][n][ri];
#pragma unroll
                for (int d = 1; d < 16; d <<= 1) ss += __shfl_xor(ss, d, 64);
                const float sc = rsqrtf(ss) * (masks[row] ? 1.0f : 0.0f);
                const int b = row >> 11, s = row & 2047;
                const size_t base = ((size_t)(b * HH + h2) * SS + s) * 64;
#pragma unroll
                for (int n = 0; n < 4; ++n)
                    dst[base + n * 16 + rl] = __float2bfloat16(acc[m][n][ri] * sc);
            }
        }
    } else {
        // fused V transpose: Vt[(b*H+h)*64 + d][s], packed 4-bf16 writes
        const int h2 = (ncol0 - 2048) >> 6;
        const int b = (m0 + wr) >> 11;
        const int sb = ((m0 + wr) & 2047) + g * 4;
#pragma unroll
        for (int m = 0; m < 2; ++m)
#pragma unroll
            for (int n = 0; n < 4; ++n) {
                const int d = n * 16 + rl;
                bf t4[4];
#pragma unroll
                for (int ri = 0; ri < 4; ++ri) t4[ri] = __float2bfloat16(acc[m][n][ri]);
                *(uint2*)&Vt[((size_t)(b * HH + h2) * 64 + d) * SS + sb + m * 16] =
                    *(uint2*)t4;
            }
    }
}

// ---------------------------------------------------------------
// Out-proj GEMM: 64x128 tile, BK=32, 4 waves, 3-buffer counted-vmcnt pipeline.
__global__ __launch_bounds__(256) void k_gemm(const bf* __restrict__ A,
                                              const bf* __restrict__ Bt,
                                              float* __restrict__ Cf,
                                              int nx, int N, int K) {
    constexpr int BM = 64, BN = 128;
    __shared__ __align__(16) bf Asm[3][BM * 32];
    __shared__ __align__(16) bf Bsm[3][BN * 32];
    const int tid = threadIdx.x;
    const int w = tid >> 6, lane = tid & 63, g = lane >> 4, rl = lane & 15;
    const int cpx = gridDim.x >> 3;
    const int swz = (blockIdx.x & 7) * cpx + (blockIdx.x >> 3);
    const int m0 = (swz / nx) * BM, n0 = (swz % nx) * BN;
    const int wr = (w >> 1) * 32, wc = (w & 1) * 64;
    const int lrow = lane >> 2, lseg = lane & 3;
    const int xseg = lseg ^ ((lrow >> 1) & 3);

    f32x4 acc[2][4] = {};
    const bf* Ap = A + (size_t)m0 * K;
    const bf* Bp = Bt + (size_t)n0 * K;

    auto stage = [&](int bi, int k0) {
        glds16(Ap + (size_t)(w * 16 + lrow) * K + k0 + xseg * 8, &Asm[bi][w * 512]);
#pragma unroll
        for (int u = 0; u < 2; ++u)
            glds16(Bp + (size_t)(u * 64 + w * 16 + lrow) * K + k0 + xseg * 8,
                   &Bsm[bi][(u * 64 + w * 16) * 32]);
    };

    const int T = K >> 5;
    stage(0, 0);
    stage(1, 32);
    int cur = 0, nxt = 2;
    for (int t = 0; t < T; ++t) {
        __builtin_amdgcn_sched_barrier(0);
        if (t < T - 1) { VMCNT(3); } else { VMCNT(0); }
        __builtin_amdgcn_s_barrier();
        __builtin_amdgcn_sched_barrier(0);
        if (t + 2 < T) stage(nxt, (t + 2) * 32);

        const bf* Ab = Asm[cur];
        const bf* Bb = Bsm[cur];
        bf16x8 af[2], bfr[4];
#pragma unroll
        for (int m = 0; m < 2; ++m) {
            const int row = wr + m * 16 + rl;
            af[m] = __builtin_bit_cast(bf16x8,
                *(const int4*)&Ab[row * 32 + (g ^ ((row >> 1) & 3)) * 8]);
        }
#pragma unroll
        for (int n = 0; n < 4; ++n) {
            const int row = wc + n * 16 + rl;
            bfr[n] = __builtin_bit_cast(bf16x8,
                *(const int4*)&Bb[row * 32 + (g ^ ((row >> 1) & 3)) * 8]);
        }
        __builtin_amdgcn_s_setprio(1);
#pragma unroll
        for (int m = 0; m < 2; ++m)
#pragma unroll
            for (int n = 0; n < 4; ++n)
                acc[m][n] = mfma16(af[m], bfr[n], acc[m][n]);
        __builtin_amdgcn_s_setprio(0);

        cur = (cur == 2) ? 0 : cur + 1;
        nxt = (nxt == 2) ? 0 : nxt + 1;
    }

#pragma unroll
    for (int m = 0; m < 2; ++m)
#pragma unroll
        for (int n = 0; n < 4; ++n)
#pragma unroll
            for (int ri = 0; ri < 4; ++ri)
                Cf[(size_t)(m0 + wr + m * 16 + g * 4 + ri) * N + n0 + wc + n * 16 + rl] =
                    acc[m][n][ri];
}

// ---------------------------------------------------------------
// Attention v6: balanced q-tile pairing + 2x fragment reuse.
// Block = (head, pair j): q-tiles j AND 31-j (64 rows each) -> all 512
// blocks have IDENTICAL work (33 tile-computes, 32-j staged tiles): no
// causal-drain. Wave (qh,kp) holds BOTH tiles' Q; each staged K/V fragment
// ds_read feeds two mfma32 (r8-proven body). Block order: XCD-chunked so
// each XCD owns 4 heads (K/V 2MB -> L2-resident). 2-buffer glds16 staging +
// single __syncthreads per tile (r10-proven). In-register P via cvt_pk +
// permlane32_swap; kp-partials summed via 32KB LDS reduce (plain add).
__global__ __launch_bounds__(256) void k_attn(const bf* __restrict__ Qn,  // [B*H,S,64]
                                              const bf* __restrict__ Kn,  // [B*H,S,64]
                                              const bf* __restrict__ Vt,  // [B*H,64,S]
                                              bf* __restrict__ Ctx) {     // [B*S, D]
    __shared__ __align__(16) bf smem[16384];      // 32KB: K[2][4096] | V[2][4096]
    bf* Ksm = smem;
    bf* Vsm = smem + 8192;

    // XCD-chunked mapping: swz-contiguous = same head (4 heads per XCD)
    const int swz = (blockIdx.x & 7) * 64 + (blockIdx.x >> 3);   // [0,512)
    const int by = swz >> 4;              // head: b*H + h
    const int j  = swz & 15;              // pair index: q-tiles j and 31-j
    const int b = by >> 4, h = by & 15;
    const int tid = threadIdx.x;
    const int w = tid >> 6, lane = tid & 63;
    const int l31 = lane & 31, hl = lane >> 5;
    const int qh = w >> 1;                // q-half within each 64-row tile
    const int kp = w & 1;                 // k-parity: subtile kb = t*64+kp*32
    const int qA = j * 64 + qh * 32;             // lo tile rows
    const int qB = (31 - j) * 64 + qh * 32;      // hi tile rows

    const bf* Qp = Qn + (size_t)by * SS * 64;
    const bf* Kp = Kn + (size_t)by * SS * 64;
    const bf* Vp = Vt + (size_t)by * 64 * SS;

    // hoisted Q (B-operand) for both tiles: col=q=l31, d = st*16 + hl*8
    bf16x8 aqsA[4], aqsB[4];
#pragma unroll
    for (int st = 0; st < 4; ++st) {
        aqsA[st] = __builtin_bit_cast(bf16x8,
            *(const int4*)(Qp + (size_t)(qA + l31) * 64 + st * 16 + hl * 8));
        aqsB[st] = __builtin_bit_cast(bf16x8,
            *(const int4*)(Qp + (size_t)(qB + l31) * 64 + st * 16 + hl * 8));
    }

    // staging: chunk c = 8 rows x 128B; pre-swizzled source slot (r10-proven)
    const int srow = lane >> 3;
    const int sblk = (lane & 7) ^ srow;

    auto stage = [&](int buf, int k0) {
#pragma unroll
        for (int u = 0; u < 2; ++u) {
            const int c = w * 2 + u;
            const int row = c * 8 + srow;
            glds16(Kp + (size_t)(k0 + row) * 64 + sblk * 8, &Ksm[buf * 4096 + c * 512]);
            glds16(Vp + (size_t)row * SS + k0 + sblk * 8, &Vsm[buf * 4096 + c * 512]);
        }
    };

    // pack: relu + causal -> bf16 PV A-frags (r8-proven)
    auto packP = [&](const f32x16& pc, int qgBase, int kb, bf16x8 (&pa)[2]) {
        const bool dg = (kb + 31 > qgBase);
        float pv[16];
#pragma unroll
        for (int m2 = 0; m2 < 16; ++m2) {
            float v = fmaxf(pc[m2], 0.0f);
            if (dg) {
                const int kg = kb + (m2 & 3) + 8 * (m2 >> 2) + 4 * hl;
                if (kg > qgBase + l31) v = 0.0f;
            }
            pv[m2] = v;
        }
        unsigned P[8];
#pragma unroll
        for (int m2 = 0; m2 < 8; ++m2) P[m2] = cvt_pk_bf16(pv[2 * m2], pv[2 * m2 + 1]);
        pl32swap(P[0], P[2]); pl32swap(P[1], P[3]);
        pl32swap(P[4], P[6]); pl32swap(P[5], P[7]);
        uint4 w0 = {P[0], P[1], P[2], P[3]}, w1 = {P[4], P[5], P[6], P[7]};
        pa[0] = __builtin_bit_cast(bf16x8, w0);
        pa[1] = __builtin_bit_cast(bf16x8, w1);
    };

    f32x16 accA[2] = {}, accB[2] = {};
    const int T = 32 - j;                 // k-tiles 0..31-j

    stage(0, 0);
    __syncthreads();
    int cur = 0;
    for (int t = 0; t < T; ++t) {
        if (t + 1 < T) stage(cur ^ 1, (t + 1) * 64);
        const int kb = t * 64 + kp * 32;
        const bool needA = (kb <= qA + 31);
        const bool needB = (kb <= qB + 31);
        if (needB || needA) {
            const bf* Ks = &Ksm[cur * 4096];
            const bf* Vs = &Vsm[cur * 4096];
            const int r = kp * 32 + l31;
            // ---- QK^T (swapped): each ak read feeds both q-tiles
            f32x16 pcA = {}, pcB = {};
#pragma unroll
            for (int st = 0; st < 4; ++st) {
                bf16x8 ak = __builtin_bit_cast(bf16x8,
                    *(const int4*)&Ks[r * 64 + (((2 * st + hl) ^ (r & 7)) << 3)]);
                if (needA) pcA = mfma32(ak, aqsA[st], pcA);
                if (needB) pcB = mfma32(ak, aqsB[st], pcB);
            }
            // ---- relu + causal + pack per tile
            bf16x8 paA[2], paB[2];
            if (needA) packP(pcA, qA, kb, paA);
            if (needB) packP(pcB, qB, kb, paB);
            // ---- PV: each bv read feeds both q-tiles
#pragma unroll
            for (int s = 0; s < 2; ++s)
#pragma unroll
                for (int dt = 0; dt < 2; ++dt) {
                    const int d = dt * 32 + l31;
                    const int slot = kp * 4 + s * 2 + hl;
                    bf16x8 bv = __builtin_bit_cast(bf16x8,
                        *(const int4*)&Vs[d * 64 + ((slot ^ (d & 7)) << 3)]);
                    if (needA) accA[dt] = mfma32(paA[s], bv, accA[dt]);
                    if (needB) accB[dt] = mfma32(paB[s], bv, accB[dt]);
                }
        }
        __syncthreads();
        cur ^= 1;
    }

    // ---- cross-wave (k-parity) reduce via 32KB LDS, then kp==0 writes Ctx
    float* red = (float*)smem;            // [2 tiles][64 q][64 d] f32 = 32KB
    if (kp == 1) {
#pragma unroll
        for (int dt = 0; dt < 2; ++dt)
#pragma unroll
            for (int m2 = 0; m2 < 16; ++m2) {
                const int crow = (m2 & 3) + 8 * (m2 >> 2) + 4 * hl;
                const int d = dt * 32 + l31;
                red[(qh * 32 + crow) * 64 + d] = accA[dt][m2];
                red[(64 + qh * 32 + crow) * 64 + d] = accB[dt][m2];
            }
    }
    __syncthreads();
    if (kp == 0) {
#pragma unroll
        for (int dt = 0; dt < 2; ++dt)
#pragma unroll
            for (int m2 = 0; m2 < 16; ++m2) {
                const int crow = (m2 & 3) + 8 * (m2 >> 2) + 4 * hl;
                const int d = dt * 32 + l31;
                const float vA = accA[dt][m2] + red[(qh * 32 + crow) * 64 + d];
                const float vB = accB[dt][m2] + red[(64 + qh * 32 + crow) * 64 + d];
                Ctx[(size_t)(b * SS + qA + crow) * DD + h * 64 + d] = __float2bfloat16(vA);
                Ctx[(size_t)(b * SS + qB + crow) * DD + h * 64 + d] = __float2bfloat16(vB);
            }
    }
}

// ---------------------------------------------------------------
extern "C" void kernel_launch(void* const* d_in, const int* in_sizes, int n_in,
                              void* d_out, int out_size, void* d_ws, size_t ws_size,
                              hipStream_t stream) {
    const float* X  = (const float*)d_in[0];
    const int* masks = (const int*)d_in[1];
    const float* Wq = (const float*)d_in[2];
    const float* Wk = (const float*)d_in[3];
    const float* Wv = (const float*)d_in[4];
    const float* Wo = (const float*)d_in[5];
    float* out = (float*)d_out;
    char* ws = (char*)d_ws;

    const size_t MB = 1024 * 1024;
    bf* Xb   = (bf*)(ws);              // 8 MB  [B*S, D]
    bf* Wqkv = (bf*)(ws + 8  * MB);    // 6 MB  [3072, 1024]
    bf* Wob  = (bf*)(ws + 14 * MB);    // 2 MB
    bf* Qn   = (bf*)(ws + 16 * MB);    // 8 MB  [B*H, S, 64]
    bf* Kn   = (bf*)(ws + 24 * MB);
    bf* Vt   = (bf*)(ws + 32 * MB);    // 8 MB  [B*H, 64, S]
    bf* Ctx  = (bf*)(ws + 40 * MB);    // 8 MB  [B*S, D]

    // converts (one launch)
    k_convert<<<8192, 256, 0, stream>>>(X, Wq, Wk, Wv, Wo, Xb, Wqkv, Wob);

    // fused QKV projection + norm/mask epilogue + V-transpose
    // (128x128 tiles -> 768 blocks, 8 waves)
    k_gemm8<<<(ND3 / 128) * (MMR / 128), 512, 0, stream>>>(
        Xb, Wqkv, masks, Qn, Kn, Vt, ND3 / 128, DD);

    // attention (balanced pairs: 16 pairs x 32 heads = 512 equal-work blocks)
    k_attn<<<512, 256, 0, stream>>>(Qn, Kn, Vt, Ctx);

    // output projection (64x128 tiles -> 512 blocks)
    k_gemm<<<(DD / 128) * (MMR / 64), 256, 0, stream>>>(
        Ctx, Wob, out, DD / 128, DD, DD);
}

// Round 13
// 102.650 us; speedup vs baseline: 1.6212x; 1.6212x over previous
//
#include <hip/hip_runtime.h>
#include <hip/hip_bf16.h>

// Problem constants
#define BB 2
#define SS 2048
#define DD 1024
#define HH 16
#define MMR (BB*SS)   // 4096 rows
#define ND3 3072      // fused QKV width

typedef __hip_bfloat16 bf;
typedef __bf16 bf16x8 __attribute__((ext_vector_type(8)));
typedef float f32x4 __attribute__((ext_vector_type(4)));
typedef float f32x16 __attribute__((ext_vector_type(16)));

#define VMCNT(n) asm volatile("s_waitcnt vmcnt(" #n ")" ::: "memory")

__device__ __forceinline__ f32x4 mfma16(bf16x8 a, bf16x8 b, f32x4 c) {
    return __builtin_amdgcn_mfma_f32_16x16x32_bf16(a, b, c, 0, 0, 0);
}
__device__ __forceinline__ f32x16 mfma32(bf16x8 a, bf16x8 b, f32x16 c) {
    return __builtin_amdgcn_mfma_f32_32x32x16_bf16(a, b, c, 0, 0, 0);
}
__device__ __forceinline__ unsigned cvt_pk_bf16(float lo, float hi) {
    unsigned r;
    asm("v_cvt_pk_bf16_f32 %0, %1, %2" : "=v"(r) : "v"(lo), "v"(hi));
    return r;
}
// after: a = {a.lo31, b.lo31}, b = {a.hi31, b.hi31}
__device__ __forceinline__ void pl32swap(unsigned& a, unsigned& b) {
    asm("v_permlane32_swap_b32 %0, %1" : "+v"(a), "+v"(b));
}
// async global->LDS, 16B/lane; LDS dest = wave-uniform base + lane*16
__device__ __forceinline__ void glds16(const bf* g, bf* l) {
    __builtin_amdgcn_global_load_lds(
        (const __attribute__((address_space(1))) void*)g,
        (__attribute__((address_space(3))) void*)l,
        16, 0, 0);
}

// ---------------------------------------------------------------
// All f32->bf16 converts in ONE launch. blocks 0..4095: X (4M elems);
// blocks 4096..8191: Wq,Wk,Wv (into Wqkv) and Wo (into Wob), 1M each.
__global__ __launch_bounds__(256) void k_convert(const float* __restrict__ X,
                                                 const float* __restrict__ Wq,
                                                 const float* __restrict__ Wk,
                                                 const float* __restrict__ Wv,
                                                 const float* __restrict__ Wo,
                                                 bf* __restrict__ Xb,
                                                 bf* __restrict__ Wqkv,
                                                 bf* __restrict__ Wob) {
    const int bid = blockIdx.x;
    const float* src;
    bf* dst;
    int off;
    if (bid < 4096) {
        src = X; dst = Xb; off = bid;
    } else {
        const int r = (bid - 4096) >> 10;
        src = (r == 0) ? Wq : (r == 1) ? Wk : (r == 2) ? Wv : Wo;
        dst = (r < 3) ? (Wqkv + (size_t)r * 1048576) : Wob;
        off = (bid - 4096) & 1023;
    }
    const int j = (off * 256 + threadIdx.x) * 4;
    float4 v = *(const float4*)(src + j);
    bf tmp[4];
    tmp[0] = __float2bfloat16(v.x);
    tmp[1] = __float2bfloat16(v.y);
    tmp[2] = __float2bfloat16(v.z);
    tmp[3] = __float2bfloat16(v.w);
    *(uint2*)(dst + j) = *(const uint2*)tmp;
}

// ---------------------------------------------------------------
// QKV GEMM (r7/r10-proven): 128x128 tile, BK=32, 8 waves (512 thr),
// wave = 32x64 quadrant. 3-buffer LDS pipeline, counted vmcnt, raw s_barrier,
// seg-XOR LDS swizzle. 768 blocks x 8 waves = 24 waves/CU.
// Fused epilogue: cols<2048 -> per-head L2-norm * mask -> Qn/Kn [B*H,S,64];
// cols>=2048 -> transposed bf16 write to Vt [B*H,64,S].
__global__ __launch_bounds__(512, 6) void k_gemm8(const bf* __restrict__ A,
                                                  const bf* __restrict__ Bt,
                                                  const int* __restrict__ masks,
                                                  bf* __restrict__ Qn,
                                                  bf* __restrict__ Kn,
                                                  bf* __restrict__ Vt,
                                                  int nx, int K) {
    __shared__ __align__(16) bf Asm[3][128 * 32];
    __shared__ __align__(16) bf Bsm[3][128 * 32];
    const int tid = threadIdx.x;
    const int w = tid >> 6, lane = tid & 63, g = lane >> 4, rl = lane & 15;
    const int cpx = gridDim.x >> 3;
    const int swz = (blockIdx.x & 7) * cpx + (blockIdx.x >> 3);
    const int m0 = (swz / nx) * 128, n0 = (swz % nx) * 128;
    const int wr = (w >> 1) * 32, wc = (w & 1) * 64;
    const int lrow = lane >> 2, lseg = lane & 3;
    const int xseg = lseg ^ ((lrow >> 1) & 3);   // pre-swizzled source seg

    f32x4 acc[2][4] = {};
    const bf* Ap = A + (size_t)m0 * K;
    const bf* Bp = Bt + (size_t)n0 * K;

    auto stage = [&](int bi, int k0) {
        glds16(Ap + (size_t)(w * 16 + lrow) * K + k0 + xseg * 8, &Asm[bi][w * 512]);
        glds16(Bp + (size_t)(w * 16 + lrow) * K + k0 + xseg * 8, &Bsm[bi][w * 512]);
    };

    const int T = K >> 5;
    stage(0, 0);
    stage(1, 32);
    int cur = 0, nxt = 2;
    for (int t = 0; t < T; ++t) {
        __builtin_amdgcn_sched_barrier(0);
        if (t < T - 1) { VMCNT(2); } else { VMCNT(0); }
        __builtin_amdgcn_s_barrier();     // staged loads stay in flight
        __builtin_amdgcn_sched_barrier(0);
        if (t + 2 < T) stage(nxt, (t + 2) * 32);

        const bf* Ab = Asm[cur];
        const bf* Bb = Bsm[cur];
        bf16x8 af[2], bfr[4];
#pragma unroll
        for (int m = 0; m < 2; ++m) {
            const int row = wr + m * 16 + rl;
            af[m] = __builtin_bit_cast(bf16x8,
                *(const int4*)&Ab[row * 32 + (g ^ ((row >> 1) & 3)) * 8]);
        }
#pragma unroll
        for (int n = 0; n < 4; ++n) {
            const int row = wc + n * 16 + rl;
            bfr[n] = __builtin_bit_cast(bf16x8,
                *(const int4*)&Bb[row * 32 + (g ^ ((row >> 1) & 3)) * 8]);
        }
        __builtin_amdgcn_s_setprio(1);
#pragma unroll
        for (int m = 0; m < 2; ++m)
#pragma unroll
            for (int n = 0; n < 4; ++n)
                acc[m][n] = mfma16(af[m], bfr[n], acc[m][n]);
        __builtin_amdgcn_s_setprio(0);

        cur = (cur == 2) ? 0 : cur + 1;
        nxt = (nxt == 2) ? 0 : nxt + 1;
    }

    const int ncol0 = n0 + wc;   // wave's 64-col base == one head slice
    if (ncol0 < 2048) {
        bf* dst = (ncol0 < 1024) ? Qn : Kn;
        const int h2 = (ncol0 >> 6) & 15;
#pragma unroll
        for (int m = 0; m < 2; ++m) {
#pragma unroll
            for (int ri = 0; ri < 4; ++ri) {
                const int row = m0 + wr + m * 16 + g * 4 + ri;   // b*S+s
                float ss = 0.f;
#pragma unroll
                for (int n = 0; n < 4; ++n) ss += acc[m][n][ri] * acc[m][n][ri];
#pragma unroll
                for (int d = 1; d < 16; d <<= 1) ss += __shfl_xor(ss, d, 64);
                const float sc = rsqrtf(ss) * (masks[row] ? 1.0f : 0.0f);
                const int b = row >> 11, s = row & 2047;
                const size_t base = ((size_t)(b * HH + h2) * SS + s) * 64;
#pragma unroll
                for (int n = 0; n < 4; ++n)
                    dst[base + n * 16 + rl] = __float2bfloat16(acc[m][n][ri] * sc);
            }
        }
    } else {
        // fused V transpose: Vt[(b*H+h)*64 + d][s], packed 4-bf16 writes
        const int h2 = (ncol0 - 2048) >> 6;
        const int b = (m0 + wr) >> 11;
        const int sb = ((m0 + wr) & 2047) + g * 4;
#pragma unroll
        for (int m = 0; m < 2; ++m)
#pragma unroll
            for (int n = 0; n < 4; ++n) {
                const int d = n * 16 + rl;
                bf t4[4];
#pragma unroll
                for (int ri = 0; ri < 4; ++ri) t4[ri] = __float2bfloat16(acc[m][n][ri]);
                *(uint2*)&Vt[((size_t)(b * HH + h2) * 64 + d) * SS + sb + m * 16] =
                    *(uint2*)t4;
            }
    }
}

// ---------------------------------------------------------------
// Out-proj GEMM: 64x128 tile, BK=32, 4 waves, 3-buffer counted-vmcnt pipeline.
__global__ __launch_bounds__(256) void k_gemm(const bf* __restrict__ A,
                                              const bf* __restrict__ Bt,
                                              float* __restrict__ Cf,
                                              int nx, int N, int K) {
    constexpr int BM = 64, BN = 128;
    __shared__ __align__(16) bf Asm[3][BM * 32];
    __shared__ __align__(16) bf Bsm[3][BN * 32];
    const int tid = threadIdx.x;
    const int w = tid >> 6, lane = tid & 63, g = lane >> 4, rl = lane & 15;
    const int cpx = gridDim.x >> 3;
    const int swz = (blockIdx.x & 7) * cpx + (blockIdx.x >> 3);
    const int m0 = (swz / nx) * BM, n0 = (swz % nx) * BN;
    const int wr = (w >> 1) * 32, wc = (w & 1) * 64;
    const int lrow = lane >> 2, lseg = lane & 3;
    const int xseg = lseg ^ ((lrow >> 1) & 3);

    f32x4 acc[2][4] = {};
    const bf* Ap = A + (size_t)m0 * K;
    const bf* Bp = Bt + (size_t)n0 * K;

    auto stage = [&](int bi, int k0) {
        glds16(Ap + (size_t)(w * 16 + lrow) * K + k0 + xseg * 8, &Asm[bi][w * 512]);
#pragma unroll
        for (int u = 0; u < 2; ++u)
            glds16(Bp + (size_t)(u * 64 + w * 16 + lrow) * K + k0 + xseg * 8,
                   &Bsm[bi][(u * 64 + w * 16) * 32]);
    };

    const int T = K >> 5;
    stage(0, 0);
    stage(1, 32);
    int cur = 0, nxt = 2;
    for (int t = 0; t < T; ++t) {
        __builtin_amdgcn_sched_barrier(0);
        if (t < T - 1) { VMCNT(3); } else { VMCNT(0); }
        __builtin_amdgcn_s_barrier();
        __builtin_amdgcn_sched_barrier(0);
        if (t + 2 < T) stage(nxt, (t + 2) * 32);

        const bf* Ab = Asm[cur];
        const bf* Bb = Bsm[cur];
        bf16x8 af[2], bfr[4];
#pragma unroll
        for (int m = 0; m < 2; ++m) {
            const int row = wr + m * 16 + rl;
            af[m] = __builtin_bit_cast(bf16x8,
                *(const int4*)&Ab[row * 32 + (g ^ ((row >> 1) & 3)) * 8]);
        }
#pragma unroll
        for (int n = 0; n < 4; ++n) {
            const int row = wc + n * 16 + rl;
            bfr[n] = __builtin_bit_cast(bf16x8,
                *(const int4*)&Bb[row * 32 + (g ^ ((row >> 1) & 3)) * 8]);
        }
        __builtin_amdgcn_s_setprio(1);
#pragma unroll
        for (int m = 0; m < 2; ++m)
#pragma unroll
            for (int n = 0; n < 4; ++n)
                acc[m][n] = mfma16(af[m], bfr[n], acc[m][n]);
        __builtin_amdgcn_s_setprio(0);

        cur = (cur == 2) ? 0 : cur + 1;
        nxt = (nxt == 2) ? 0 : nxt + 1;
    }

#pragma unroll
    for (int m = 0; m < 2; ++m)
#pragma unroll
        for (int n = 0; n < 4; ++n)
#pragma unroll
            for (int ri = 0; ri < 4; ++ri)
                Cf[(size_t)(m0 + wr + m * 16 + g * 4 + ri) * N + n0 + wc + n * 16 + rl] =
                    acc[m][n][ri];
}

// ---------------------------------------------------------------
// Attention (r4/r10-proven best, 42us): 32x32 MFMA + in-register P (T12),
// q-tile 64, 1024 blocks (LPT). 4 waves = (q-half qh) x (k-parity kp).
// 2-buffer K/V staged via glds16 (XOR-swizzled source), single __syncthreads
// per tile (stage next -> compute current -> sync). Partial O's summed via
// one-time LDS reduce (no softmax -> plain add).
__global__ __launch_bounds__(256) void k_attn(const bf* __restrict__ Qn,  // [B*H,S,64]
                                              const bf* __restrict__ Kn,  // [B*H,S,64]
                                              const bf* __restrict__ Vt,  // [B*H,64,S]
                                              bf* __restrict__ Ctx) {     // [B*S, D]
    __shared__ __align__(16) bf Ksm[2][64 * 64];  // [kv][d], 16KB
    __shared__ __align__(16) bf Vsm[2][64 * 64];  // [d][kv], 16KB

    const int idx = blockIdx.x;
    const int qt = 31 - (idx >> 5);       // 0..31, largest-first (LPT)
    const int by = idx & 31;              // b*H + h
    const int b = by >> 4, h = by & 15;
    const int tid = threadIdx.x;
    const int w = tid >> 6, lane = tid & 63;
    const int l31 = lane & 31, hl = lane >> 5;
    const int qh = w >> 1;                // q-half: rows qt*64+qh*32 ..+32
    const int kp = w & 1;                 // k-parity: handles subtile kb=t*64+kp*32
    const int qw = qt * 64 + qh * 32;
    const int qg = qw + l31;

    const bf* Qp = Qn + (size_t)by * SS * 64;
    const bf* Kp = Kn + (size_t)by * SS * 64;
    const bf* Vp = Vt + (size_t)by * 64 * SS;

    // hoisted Q (B-operand): col=q=l31, d = st*16 + hl*8 + 0..7
    bf16x8 aqs[4];
#pragma unroll
    for (int st = 0; st < 4; ++st)
        aqs[st] = __builtin_bit_cast(bf16x8,
            *(const int4*)(Qp + (size_t)(qw + l31) * 64 + st * 16 + hl * 8));

    // staging: chunk c = 8 rows x 128B; pre-swizzled source slot
    const int srow = lane >> 3;
    const int sblk = (lane & 7) ^ srow;

    auto stage = [&](int buf, int k0) {
#pragma unroll
        for (int u = 0; u < 2; ++u) {
            const int c = w * 2 + u;
            const int row = c * 8 + srow;
            glds16(Kp + (size_t)(k0 + row) * 64 + sblk * 8, &Ksm[buf][c * 512]);
            glds16(Vp + (size_t)row * SS + k0 + sblk * 8, &Vsm[buf][c * 512]);
        }
    };

    f32x16 accd[2] = {};

    stage(0, 0);
    __syncthreads();
    int cur = 0;
    for (int t = 0; t <= qt; ++t) {
        if (t < qt) stage(cur ^ 1, (t + 1) * 64);
        const int kb = t * 64 + kp * 32;
        if (kb <= qw + 31) {
            // ---- QK^T (swapped): D[row=k][col=q]
            f32x16 pc = {};
#pragma unroll
            for (int st = 0; st < 4; ++st) {
                const int r = kp * 32 + l31;
                bf16x8 ak = __builtin_bit_cast(bf16x8,
                    *(const int4*)&Ksm[cur][r * 64 + (((2 * st + hl) ^ (r & 7)) << 3)]);
                pc = mfma32(ak, aqs[st], pc);
            }
            // ---- relu + causal (elementwise only near diagonal)
            const bool dg = (kb + 31 > qw);
            float pv[16];
#pragma unroll
            for (int m2 = 0; m2 < 16; ++m2) {
                float v = fmaxf(pc[m2], 0.0f);
                if (dg) {
                    const int kg = kb + (m2 & 3) + 8 * (m2 >> 2) + 4 * hl;
                    if (kg > qg) v = 0.0f;
                }
                pv[m2] = v;
            }
            // ---- pack to bf16 pairs + permlane swaps -> PV A-frags (no LDS)
            unsigned P[8];
#pragma unroll
            for (int m2 = 0; m2 < 8; ++m2) P[m2] = cvt_pk_bf16(pv[2 * m2], pv[2 * m2 + 1]);
            pl32swap(P[0], P[2]);
            pl32swap(P[1], P[3]);
            pl32swap(P[4], P[6]);
            pl32swap(P[5], P[7]);
            // ---- PV: D[row=q][col=d]
#pragma unroll
            for (int s = 0; s < 2; ++s) {
                uint4 pw = {P[4 * s + 0], P[4 * s + 1], P[4 * s + 2], P[4 * s + 3]};
                bf16x8 pa = __builtin_bit_cast(bf16x8, pw);
#pragma unroll
                for (int dt = 0; dt < 2; ++dt) {
                    const int d = dt * 32 + l31;
                    const int slot = kp * 4 + s * 2 + hl;
                    bf16x8 bv = __builtin_bit_cast(bf16x8,
                        *(const int4*)&Vsm[cur][d * 64 + ((slot ^ (d & 7)) << 3)]);
                    accd[dt] = mfma32(pa, bv, accd[dt]);
                }
            }
        }
        __syncthreads();
        cur ^= 1;
    }

    // ---- cross-wave (k-parity) reduce via LDS, then kp==0 writes Ctx
    float* red = (float*)&Ksm[0][0];      // 16KB: 2 q-halves x 8KB
    if (kp == 1) {
#pragma unroll
        for (int dt = 0; dt < 2; ++dt)
#pragma unroll
            for (int m2 = 0; m2 < 16; ++m2)
                red[qh * 2048 + (dt * 16 + m2) * 64 + lane] = accd[dt][m2];
    }
    __syncthreads();
    if (kp == 0) {
#pragma unroll
        for (int dt = 0; dt < 2; ++dt)
#pragma unroll
            for (int m2 = 0; m2 < 16; ++m2) {
                const float v = accd[dt][m2] + red[qh * 2048 + (dt * 16 + m2) * 64 + lane];
                const int q = qw + (m2 & 3) + 8 * (m2 >> 2) + 4 * hl;
                const int d = dt * 32 + l31;
                Ctx[(size_t)(b * SS + q) * DD + h * 64 + d] = __float2bfloat16(v);
            }
    }
}

// ---------------------------------------------------------------
extern "C" void kernel_launch(void* const* d_in, const int* in_sizes, int n_in,
                              void* d_out, int out_size, void* d_ws, size_t ws_size,
                              hipStream_t stream) {
    const float* X  = (const float*)d_in[0];
    const int* masks = (const int*)d_in[1];
    const float* Wq = (const float*)d_in[2];
    const float* Wk = (const float*)d_in[3];
    const float* Wv = (const float*)d_in[4];
    const float* Wo = (const float*)d_in[5];
    float* out = (float*)d_out;
    char* ws = (char*)d_ws;

    const size_t MB = 1024 * 1024;
    bf* Xb   = (bf*)(ws);              // 8 MB  [B*S, D]
    bf* Wqkv = (bf*)(ws + 8  * MB);    // 6 MB  [3072, 1024]
    bf* Wob  = (bf*)(ws + 14 * MB);    // 2 MB
    bf* Qn   = (bf*)(ws + 16 * MB);    // 8 MB  [B*H, S, 64]
    bf* Kn   = (bf*)(ws + 24 * MB);
    bf* Vt   = (bf*)(ws + 32 * MB);    // 8 MB  [B*H, 64, S]
    bf* Ctx  = (bf*)(ws + 40 * MB);    // 8 MB  [B*S, D]

    // converts (one launch)
    k_convert<<<8192, 256, 0, stream>>>(X, Wq, Wk, Wv, Wo, Xb, Wqkv, Wob);

    // fused QKV projection + norm/mask epilogue + V-transpose
    // (128x128 tiles -> 768 blocks, 8 waves)
    k_gemm8<<<(ND3 / 128) * (MMR / 128), 512, 0, stream>>>(
        Xb, Wqkv, masks, Qn, Kn, Vt, ND3 / 128, DD);

    // attention (r4/r10 structure: 2-buffer, 1024 blocks)
    k_attn<<<1024, 256, 0, stream>>>(Qn, Kn, Vt, Ctx);

    // output projection (64x128 tiles -> 512 blocks)
    k_gemm<<<(DD / 128) * (MMR / 64), 256, 0, stream>>>(
        Ctx, Wob, out, DD / 128, DD, DD);
}

// Round 14
// 95.713 us; speedup vs baseline: 1.7386x; 1.0725x over previous
//
#include <hip/hip_runtime.h>
#include <hip/hip_bf16.h>

// Problem constants
#define BB 2
#define SS 2048
#define DD 1024
#define HH 16
#define MMR (BB*SS)   // 4096 rows
#define ND3 3072      // fused QKV width

typedef __hip_bfloat16 bf;
typedef __bf16 bf16x8 __attribute__((ext_vector_type(8)));
typedef float f32x4 __attribute__((ext_vector_type(4)));
typedef float f32x16 __attribute__((ext_vector_type(16)));

#define VMCNT(n) asm volatile("s_waitcnt vmcnt(" #n ")" ::: "memory")

__device__ __forceinline__ f32x4 mfma16(bf16x8 a, bf16x8 b, f32x4 c) {
    return __builtin_amdgcn_mfma_f32_16x16x32_bf16(a, b, c, 0, 0, 0);
}
__device__ __forceinline__ f32x16 mfma32(bf16x8 a, bf16x8 b, f32x16 c) {
    return __builtin_amdgcn_mfma_f32_32x32x16_bf16(a, b, c, 0, 0, 0);
}
__device__ __forceinline__ unsigned cvt_pk_bf16(float lo, float hi) {
    unsigned r;
    asm("v_cvt_pk_bf16_f32 %0, %1, %2" : "=v"(r) : "v"(lo), "v"(hi));
    return r;
}
// after: a = {a.lo31, b.lo31}, b = {a.hi31, b.hi31}
__device__ __forceinline__ void pl32swap(unsigned& a, unsigned& b) {
    asm("v_permlane32_swap_b32 %0, %1" : "+v"(a), "+v"(b));
}
// async global->LDS, 16B/lane; LDS dest = wave-uniform base + lane*16
__device__ __forceinline__ void glds16(const bf* g, bf* l) {
    __builtin_amdgcn_global_load_lds(
        (const __attribute__((address_space(1))) void*)g,
        (__attribute__((address_space(3))) void*)l,
        16, 0, 0);
}

// ---------------------------------------------------------------
// All f32->bf16 converts in ONE launch. blocks 0..4095: X (4M elems);
// blocks 4096..8191: Wq,Wk,Wv (into Wqkv) and Wo (into Wob), 1M each.
__global__ __launch_bounds__(256) void k_convert(const float* __restrict__ X,
                                                 const float* __restrict__ Wq,
                                                 const float* __restrict__ Wk,
                                                 const float* __restrict__ Wv,
                                                 const float* __restrict__ Wo,
                                                 bf* __restrict__ Xb,
                                                 bf* __restrict__ Wqkv,
                                                 bf* __restrict__ Wob) {
    const int bid = blockIdx.x;
    const float* src;
    bf* dst;
    int off;
    if (bid < 4096) {
        src = X; dst = Xb; off = bid;
    } else {
        const int r = (bid - 4096) >> 10;
        src = (r == 0) ? Wq : (r == 1) ? Wk : (r == 2) ? Wv : Wo;
        dst = (r < 3) ? (Wqkv + (size_t)r * 1048576) : Wob;
        off = (bid - 4096) & 1023;
    }
    const int j = (off * 256 + threadIdx.x) * 4;
    float4 v = *(const float4*)(src + j);
    bf tmp[4];
    tmp[0] = __float2bfloat16(v.x);
    tmp[1] = __float2bfloat16(v.y);
    tmp[2] = __float2bfloat16(v.z);
    tmp[3] = __float2bfloat16(v.w);
    *(uint2*)(dst + j) = *(const uint2*)tmp;
}

// ---------------------------------------------------------------
// QKV GEMM (r7/r10-proven): 128x128 tile, BK=32, 8 waves (512 thr),
// wave = 32x64 quadrant. 3-buffer LDS pipeline, counted vmcnt, raw s_barrier,
// seg-XOR LDS swizzle. 768 blocks x 8 waves = 24 waves/CU.
// Fused epilogue: cols<2048 -> per-head L2-norm * mask -> Qn/Kn [B*H,S,64];
// cols>=2048 -> transposed bf16 write to Vt [B*H,64,S].
__global__ __launch_bounds__(512, 6) void k_gemm8(const bf* __restrict__ A,
                                                  const bf* __restrict__ Bt,
                                                  const int* __restrict__ masks,
                                                  bf* __restrict__ Qn,
                                                  bf* __restrict__ Kn,
                                                  bf* __restrict__ Vt,
                                                  int nx, int K) {
    __shared__ __align__(16) bf Asm[3][128 * 32];
    __shared__ __align__(16) bf Bsm[3][128 * 32];
    const int tid = threadIdx.x;
    const int w = tid >> 6, lane = tid & 63, g = lane >> 4, rl = lane & 15;
    const int cpx = gridDim.x >> 3;
    const int swz = (blockIdx.x & 7) * cpx + (blockIdx.x >> 3);
    const int m0 = (swz / nx) * 128, n0 = (swz % nx) * 128;
    const int wr = (w >> 1) * 32, wc = (w & 1) * 64;
    const int lrow = lane >> 2, lseg = lane & 3;
    const int xseg = lseg ^ ((lrow >> 1) & 3);   // pre-swizzled source seg

    f32x4 acc[2][4] = {};
    const bf* Ap = A + (size_t)m0 * K;
    const bf* Bp = Bt + (size_t)n0 * K;

    auto stage = [&](int bi, int k0) {
        glds16(Ap + (size_t)(w * 16 + lrow) * K + k0 + xseg * 8, &Asm[bi][w * 512]);
        glds16(Bp + (size_t)(w * 16 + lrow) * K + k0 + xseg * 8, &Bsm[bi][w * 512]);
    };

    const int T = K >> 5;
    stage(0, 0);
    stage(1, 32);
    int cur = 0, nxt = 2;
    for (int t = 0; t < T; ++t) {
        __builtin_amdgcn_sched_barrier(0);
        if (t < T - 1) { VMCNT(2); } else { VMCNT(0); }
        __builtin_amdgcn_s_barrier();     // staged loads stay in flight
        __builtin_amdgcn_sched_barrier(0);
        if (t + 2 < T) stage(nxt, (t + 2) * 32);

        const bf* Ab = Asm[cur];
        const bf* Bb = Bsm[cur];
        bf16x8 af[2], bfr[4];
#pragma unroll
        for (int m = 0; m < 2; ++m) {
            const int row = wr + m * 16 + rl;
            af[m] = __builtin_bit_cast(bf16x8,
                *(const int4*)&Ab[row * 32 + (g ^ ((row >> 1) & 3)) * 8]);
        }
#pragma unroll
        for (int n = 0; n < 4; ++n) {
            const int row = wc + n * 16 + rl;
            bfr[n] = __builtin_bit_cast(bf16x8,
                *(const int4*)&Bb[row * 32 + (g ^ ((row >> 1) & 3)) * 8]);
        }
        __builtin_amdgcn_s_setprio(1);
#pragma unroll
        for (int m = 0; m < 2; ++m)
#pragma unroll
            for (int n = 0; n < 4; ++n)
                acc[m][n] = mfma16(af[m], bfr[n], acc[m][n]);
        __builtin_amdgcn_s_setprio(0);

        cur = (cur == 2) ? 0 : cur + 1;
        nxt = (nxt == 2) ? 0 : nxt + 1;
    }

    const int ncol0 = n0 + wc;   // wave's 64-col base == one head slice
    if (ncol0 < 2048) {
        bf* dst = (ncol0 < 1024) ? Qn : Kn;
        const int h2 = (ncol0 >> 6) & 15;
#pragma unroll
        for (int m = 0; m < 2; ++m) {
#pragma unroll
            for (int ri = 0; ri < 4; ++ri) {
                const int row = m0 + wr + m * 16 + g * 4 + ri;   // b*S+s
                float ss = 0.f;
#pragma unroll
                for (int n = 0; n < 4; ++n) ss += acc[m][n][ri] * acc[m][n][ri];
#pragma unroll
                for (int d = 1; d < 16; d <<= 1) ss += __shfl_xor(ss, d, 64);
                const float sc = rsqrtf(ss) * (masks[row] ? 1.0f : 0.0f);
                const int b = row >> 11, s = row & 2047;
                const size_t base = ((size_t)(b * HH + h2) * SS + s) * 64;
#pragma unroll
                for (int n = 0; n < 4; ++n)
                    dst[base + n * 16 + rl] = __float2bfloat16(acc[m][n][ri] * sc);
            }
        }
    } else {
        // fused V transpose: Vt[(b*H+h)*64 + d][s], packed 4-bf16 writes
        const int h2 = (ncol0 - 2048) >> 6;
        const int b = (m0 + wr) >> 11;
        const int sb = ((m0 + wr) & 2047) + g * 4;
#pragma unroll
        for (int m = 0; m < 2; ++m)
#pragma unroll
            for (int n = 0; n < 4; ++n) {
                const int d = n * 16 + rl;
                bf t4[4];
#pragma unroll
                for (int ri = 0; ri < 4; ++ri) t4[ri] = __float2bfloat16(acc[m][n][ri]);
                *(uint2*)&Vt[((size_t)(b * HH + h2) * 64 + d) * SS + sb + m * 16] =
                    *(uint2*)t4;
            }
    }
}

// ---------------------------------------------------------------
// Out-proj GEMM: 64x128 tile, BK=32, 4 waves, 3-buffer counted-vmcnt pipeline.
__global__ __launch_bounds__(256) void k_gemm(const bf* __restrict__ A,
                                              const bf* __restrict__ Bt,
                                              float* __restrict__ Cf,
                                              int nx, int N, int K) {
    constexpr int BM = 64, BN = 128;
    __shared__ __align__(16) bf Asm[3][BM * 32];
    __shared__ __align__(16) bf Bsm[3][BN * 32];
    const int tid = threadIdx.x;
    const int w = tid >> 6, lane = tid & 63, g = lane >> 4, rl = lane & 15;
    const int cpx = gridDim.x >> 3;
    const int swz = (blockIdx.x & 7) * cpx + (blockIdx.x >> 3);
    const int m0 = (swz / nx) * BM, n0 = (swz % nx) * BN;
    const int wr = (w >> 1) * 32, wc = (w & 1) * 64;
    const int lrow = lane >> 2, lseg = lane & 3;
    const int xseg = lseg ^ ((lrow >> 1) & 3);

    f32x4 acc[2][4] = {};
    const bf* Ap = A + (size_t)m0 * K;
    const bf* Bp = Bt + (size_t)n0 * K;

    auto stage = [&](int bi, int k0) {
        glds16(Ap + (size_t)(w * 16 + lrow) * K + k0 + xseg * 8, &Asm[bi][w * 512]);
#pragma unroll
        for (int u = 0; u < 2; ++u)
            glds16(Bp + (size_t)(u * 64 + w * 16 + lrow) * K + k0 + xseg * 8,
                   &Bsm[bi][(u * 64 + w * 16) * 32]);
    };

    const int T = K >> 5;
    stage(0, 0);
    stage(1, 32);
    int cur = 0, nxt = 2;
    for (int t = 0; t < T; ++t) {
        __builtin_amdgcn_sched_barrier(0);
        if (t < T - 1) { VMCNT(3); } else { VMCNT(0); }
        __builtin_amdgcn_s_barrier();
        __builtin_amdgcn_sched_barrier(0);
        if (t + 2 < T) stage(nxt, (t + 2) * 32);

        const bf* Ab = Asm[cur];
        const bf* Bb = Bsm[cur];
        bf16x8 af[2], bfr[4];
#pragma unroll
        for (int m = 0; m < 2; ++m) {
            const int row = wr + m * 16 + rl;
            af[m] = __builtin_bit_cast(bf16x8,
                *(const int4*)&Ab[row * 32 + (g ^ ((row >> 1) & 3)) * 8]);
        }
#pragma unroll
        for (int n = 0; n < 4; ++n) {
            const int row = wc + n * 16 + rl;
            bfr[n] = __builtin_bit_cast(bf16x8,
                *(const int4*)&Bb[row * 32 + (g ^ ((row >> 1) & 3)) * 8]);
        }
        __builtin_amdgcn_s_setprio(1);
#pragma unroll
        for (int m = 0; m < 2; ++m)
#pragma unroll
            for (int n = 0; n < 4; ++n)
                acc[m][n] = mfma16(af[m], bfr[n], acc[m][n]);
        __builtin_amdgcn_s_setprio(0);

        cur = (cur == 2) ? 0 : cur + 1;
        nxt = (nxt == 2) ? 0 : nxt + 1;
    }

#pragma unroll
    for (int m = 0; m < 2; ++m)
#pragma unroll
        for (int n = 0; n < 4; ++n)
#pragma unroll
            for (int ri = 0; ri < 4; ++ri)
                Cf[(size_t)(m0 + wr + m * 16 + g * 4 + ri) * N + n0 + wc + n * 16 + rl] =
                    acc[m][n][ri];
}

// ---------------------------------------------------------------
// Attention v7: r10 algorithm with VALU-lean loop. Main k-loop manually
// unrolled by 2 so the LDS buffer index is COMPILE-TIME in each half ->
// all ds_read/ds_write addresses fold to loop-invariant VGPR + offset:
// immediates (buffer1 = buffer0 + 8192B fits the 16-bit DS offset field).
// Staging uses running global pointers (+= stride) instead of per-tile
// 64-bit address recompute. Compute body / pack path / masks / reduce are
// r10-verbatim (proven correct).
__global__ __launch_bounds__(256) void k_attn(const bf* __restrict__ Qn,  // [B*H,S,64]
                                              const bf* __restrict__ Kn,  // [B*H,S,64]
                                              const bf* __restrict__ Vt,  // [B*H,64,S]
                                              bf* __restrict__ Ctx) {     // [B*S, D]
    __shared__ __align__(16) bf Ksm[2][64 * 64];  // [kv][d], 16KB
    __shared__ __align__(16) bf Vsm[2][64 * 64];  // [d][kv], 16KB

    const int idx = blockIdx.x;
    const int qt = 31 - (idx >> 5);       // 0..31, largest-first (LPT)
    const int by = idx & 31;              // b*H + h
    const int b = by >> 4, h = by & 15;
    const int tid = threadIdx.x;
    const int w = tid >> 6, lane = tid & 63;
    const int l31 = lane & 31, hl = lane >> 5;
    const int qh = w >> 1;                // q-half: rows qt*64+qh*32 ..+32
    const int kp = w & 1;                 // k-parity: handles subtile kb=t*64+kp*32
    const int qw = qt * 64 + qh * 32;
    const int qg = qw + l31;

    const bf* Qp = Qn + (size_t)by * SS * 64;
    const bf* Kp = Kn + (size_t)by * SS * 64;
    const bf* Vp = Vt + (size_t)by * 64 * SS;

    // hoisted Q (B-operand): col=q=l31, d = st*16 + hl*8 + 0..7
    bf16x8 aqs[4];
#pragma unroll
    for (int st = 0; st < 4; ++st)
        aqs[st] = __builtin_bit_cast(bf16x8,
            *(const int4*)(Qp + (size_t)(qw + l31) * 64 + st * 16 + hl * 8));

    // staging: chunk c = w*2+u = 8 rows x 128B; pre-swizzled source slot
    const int srow = lane >> 3;
    const int sblk = (lane & 7) ^ srow;

    // running source pointers (strength-reduced): tile t adds 4096 (K) / 64 (V)
    const bf* ksr = Kp + (size_t)(w * 16 + srow) * 64 + sblk * 8;   // chunk w*2, u=0
    const bf* vsr = Vp + (size_t)(w * 16 + srow) * SS + sblk * 8;
    bf* const kdst = &Ksm[0][w * 1024];    // chunks w*2, w*2+1 (u offset +512)
    bf* const vdst = &Vsm[0][w * 1024];

    auto stageP = [&](int buf, const bf* ks, const bf* vs) {
        glds16(ks,            kdst + buf * 4096);
        glds16(ks + 512,      kdst + buf * 4096 + 512);     // u=1: +8 K-rows
        glds16(vs,            vdst + buf * 4096);
        glds16(vs + 8 * SS,   vdst + buf * 4096 + 512);     // u=1: +8 d-rows
    };

    f32x16 accd[2] = {};

    // per-tile compute; Ks/Vs are compile-time buffer bases at each call site
    auto doTile = [&](const bf* Ks, const bf* Vs, int t) {
        const int kb = t * 64 + kp * 32;
        if (kb > qw + 31) return;
        // ---- QK^T (swapped): D[row=k][col=q]
        f32x16 pc = {};
        const int r = kp * 32 + l31;
#pragma unroll
        for (int st = 0; st < 4; ++st) {
            bf16x8 ak = __builtin_bit_cast(bf16x8,
                *(const int4*)&Ks[r * 64 + (((2 * st + hl) ^ (r & 7)) << 3)]);
            pc = mfma32(ak, aqs[st], pc);
        }
        // ---- relu + causal (elementwise only near diagonal)
        const bool dg = (kb + 31 > qw);
        float pv[16];
#pragma unroll
        for (int m2 = 0; m2 < 16; ++m2) {
            float v = fmaxf(pc[m2], 0.0f);
            if (dg) {
                const int kg = kb + (m2 & 3) + 8 * (m2 >> 2) + 4 * hl;
                if (kg > qg) v = 0.0f;
            }
            pv[m2] = v;
        }
        // ---- pack to bf16 pairs + permlane swaps -> PV A-frags (no LDS)
        unsigned P[8];
#pragma unroll
        for (int m2 = 0; m2 < 8; ++m2) P[m2] = cvt_pk_bf16(pv[2 * m2], pv[2 * m2 + 1]);
        pl32swap(P[0], P[2]);
        pl32swap(P[1], P[3]);
        pl32swap(P[4], P[6]);
        pl32swap(P[5], P[7]);
        // ---- PV: D[row=q][col=d]
#pragma unroll
        for (int s = 0; s < 2; ++s) {
            uint4 pw = {P[4 * s + 0], P[4 * s + 1], P[4 * s + 2], P[4 * s + 3]};
            bf16x8 pa = __builtin_bit_cast(bf16x8, pw);
#pragma unroll
            for (int dt = 0; dt < 2; ++dt) {
                const int d = dt * 32 + l31;
                const int slot = kp * 4 + s * 2 + hl;
                bf16x8 bv = __builtin_bit_cast(bf16x8,
                    *(const int4*)&Vs[d * 64 + ((slot ^ (d & 7)) << 3)]);
                accd[dt] = mfma32(pa, bv, accd[dt]);
            }
        }
    };

    // prologue: tile 0 into buffer 0
    stageP(0, ksr, vsr);
    ksr += 4096; vsr += 64;
    __syncthreads();

    // pair-unrolled loop: buffer0 = even tiles, buffer1 = odd tiles
    int t = 0;
    while (t + 1 <= qt) {
        // A: compute buffer0 (tile t), prefetch tile t+1 into buffer1
        stageP(1, ksr, vsr);
        ksr += 4096; vsr += 64;
        doTile(&Ksm[0][0], &Vsm[0][0], t);
        __syncthreads();
        // B: compute buffer1 (tile t+1), prefetch tile t+2 into buffer0
        if (t + 2 <= qt) {
            stageP(0, ksr, vsr);
            ksr += 4096; vsr += 64;
        }
        doTile(&Ksm[1][0], &Vsm[1][0], t + 1);
        __syncthreads();
        t += 2;
    }
    if (t <= qt) {                        // even qt tail: tile t in buffer0
        doTile(&Ksm[0][0], &Vsm[0][0], t);
        __syncthreads();
    }

    // ---- cross-wave (k-parity) reduce via LDS, then kp==0 writes Ctx
    float* red = (float*)&Ksm[0][0];      // 16KB: 2 q-halves x 8KB
    if (kp == 1) {
#pragma unroll
        for (int dt = 0; dt < 2; ++dt)
#pragma unroll
            for (int m2 = 0; m2 < 16; ++m2)
                red[qh * 2048 + (dt * 16 + m2) * 64 + lane] = accd[dt][m2];
    }
    __syncthreads();
    if (kp == 0) {
#pragma unroll
        for (int dt = 0; dt < 2; ++dt)
#pragma unroll
            for (int m2 = 0; m2 < 16; ++m2) {
                const float v = accd[dt][m2] + red[qh * 2048 + (dt * 16 + m2) * 64 + lane];
                const int q = qw + (m2 & 3) + 8 * (m2 >> 2) + 4 * hl;
                const int d = dt * 32 + l31;
                Ctx[(size_t)(b * SS + q) * DD + h * 64 + d] = __float2bfloat16(v);
            }
    }
}

// ---------------------------------------------------------------
extern "C" void kernel_launch(void* const* d_in, const int* in_sizes, int n_in,
                              void* d_out, int out_size, void* d_ws, size_t ws_size,
                              hipStream_t stream) {
    const float* X  = (const float*)d_in[0];
    const int* masks = (const int*)d_in[1];
    const float* Wq = (const float*)d_in[2];
    const float* Wk = (const float*)d_in[3];
    const float* Wv = (const float*)d_in[4];
    const float* Wo = (const float*)d_in[5];
    float* out = (float*)d_out;
    char* ws = (char*)d_ws;

    const size_t MB = 1024 * 1024;
    bf* Xb   = (bf*)(ws);              // 8 MB  [B*S, D]
    bf* Wqkv = (bf*)(ws + 8  * MB);    // 6 MB  [3072, 1024]
    bf* Wob  = (bf*)(ws + 14 * MB);    // 2 MB
    bf* Qn   = (bf*)(ws + 16 * MB);    // 8 MB  [B*H, S, 64]
    bf* Kn   = (bf*)(ws + 24 * MB);
    bf* Vt   = (bf*)(ws + 32 * MB);    // 8 MB  [B*H, 64, S]
    bf* Ctx  = (bf*)(ws + 40 * MB);    // 8 MB  [B*S, D]

    // converts (one launch)
    k_convert<<<8192, 256, 0, stream>>>(X, Wq, Wk, Wv, Wo, Xb, Wqkv, Wob);

    // fused QKV projection + norm/mask epilogue + V-transpose
    // (128x128 tiles -> 768 blocks, 8 waves)
    k_gemm8<<<(ND3 / 128) * (MMR / 128), 512, 0, stream>>>(
        Xb, Wqkv, masks, Qn, Kn, Vt, ND3 / 128, DD);

    // attention (r10 algorithm, VALU-lean pair-unrolled loop)
    k_attn<<<1024, 256, 0, stream>>>(Qn, Kn, Vt, Ctx);

    // output projection (64x128 tiles -> 512 blocks)
    k_gemm<<<(DD / 128) * (MMR / 64), 256, 0, stream>>>(
        Ctx, Wob, out, DD / 128, DD, DD);
}